// Round 6
// baseline (2385.734 us; speedup 1.0000x reference)
//
#include <hip/hip_runtime.h>

namespace {

typedef __attribute__((ext_vector_type(8))) short short8;   // 8 bf16 (4 VGPRs)
typedef __attribute__((ext_vector_type(4))) float f32x4;

constexpr int T_LEN = 512;
constexpr int TC    = 16;    // timesteps per x-staging chunk
constexpr int HSTR  = 40;    // h-plane row stride in shorts (32 + 8 pad, 80B)
constexpr int XSTR  = 520;   // x row stride in shorts (16t * 32 + 8 pad, 1040B)

__device__ __forceinline__ float fsig(float x) {
    return __builtin_amdgcn_rcpf(1.0f + __expf(-x));
}
__device__ __forceinline__ float ftanh(float x) {
    return 2.0f * __builtin_amdgcn_rcpf(1.0f + __expf(-2.0f * x)) - 1.0f;
}
__device__ __forceinline__ f32x4 mfma16(short8 a, short8 b, f32x4 c) {
    return __builtin_amdgcn_mfma_f32_16x16x32_bf16(a, b, c, 0, 0, 0);
}
// pack bf16-truncations of (a,b) into one dword, b in LOW short
__device__ __forceinline__ unsigned permhi(float a, float b) {
    return __builtin_amdgcn_perm(__float_as_uint(a), __float_as_uint(b), 0x07060302u);
}
__device__ __forceinline__ float lo_resid(float v) {
    return v - __uint_as_float(__float_as_uint(v) & 0xffff0000u);
}
__device__ __forceinline__ short hi16(float v) {
    return (short)(__float_as_uint(v) >> 16);
}

// block = 256 threads = 4 waves over the SAME 16 batch rows.
// wid 0,1 = layer-1 stage (step t): redundant MFMA, activations split by C-row half.
// wid 2,3 = layer-2 stage (step t-1): same split. One barrier per step.
__global__ __launch_bounds__(256, 1)
void lstm2_pipe4_kernel(const float* __restrict__ x,
                        const float* __restrict__ Wih0, const float* __restrict__ Whh0,
                        const float* __restrict__ bih0, const float* __restrict__ bhh0,
                        const float* __restrict__ Wih1, const float* __restrict__ Whh1,
                        const float* __restrict__ bih1, const float* __restrict__ bhh1,
                        const float* __restrict__ W1, const float* __restrict__ b1,
                        const float* __restrict__ W2, const float* __restrict__ b2,
                        float* __restrict__ out)
{
    __shared__ __align__(16) short sh1hi[2][16 * HSTR], sh1lo[2][16 * HSTR]; // h1 ring
    __shared__ __align__(16) short sh2hi[16 * HSTR],    sh2lo[16 * HSTR];    // h2 planes
    __shared__ __align__(16) short sx[16 * XSTR];   // x chunk: per t, [hi(16)|lo(16)]

    const int tid   = threadIdx.x;
    const int wid   = tid >> 6;          // 0,1 = L1 ; 2,3 = L2
    const int lane  = tid & 63;
    const int q     = lane >> 4;         // quad
    const int n     = lane & 15;         // MFMA col (B) / batch row (A)
    const bool isL1 = (wid < 2);
    const int rbase = (wid & 1) * 2;     // activation row half: {0,1} or {2,3}

    // ---- zero h planes ----
    for (int i = tid; i < 16 * HSTR; i += 256) {
        sh1hi[0][i] = 0; sh1hi[1][i] = 0; sh1lo[0][i] = 0; sh1lo[1][i] = 0;
        sh2hi[i] = 0;    sh2lo[i] = 0;
    }

    // ---- persistent weight B-fragments + bias C-operands ----
    // chunk c = gate*2 + p ; lane-col n <-> unit (2n+p).
    // L1: frag0 k=h1_{t-1}(32);  frag1 k 0..15 = x_hi zone, 16..31 = x_lo zone
    //     bh[c][1] = [Wih_hi | Wih_hi], bl[c][1] = [Wih_lo | 0]
    // L2: frag0 k=h1_t(32); frag1 k=h2_{t-1}(32)
    short8 bh[8][2], bl[8][2];
    f32x4  bsp[8];
    #pragma unroll
    for (int c = 0; c < 8; ++c) {
        const int gate = c >> 1, p = c & 1;
        const int row  = gate * 32 + 2 * n + p;
        #pragma unroll
        for (int e = 0; e < 8; ++e) {
            const int k = q * 8 + e;
            // frag0
            const float v0 = isL1 ? Whh0[row * 32 + k] : Wih1[row * 32 + k];
            bh[c][0][e] = hi16(v0);
            bl[c][0][e] = hi16(lo_resid(v0));
            // frag1
            if (isL1) {
                const float w = Wih0[row * 16 + (k & 15)];
                bh[c][1][e] = hi16(w);
                bl[c][1][e] = (k < 16) ? hi16(lo_resid(w)) : (short)0;
            } else {
                const float v1 = Whh1[row * 32 + k];
                bh[c][1][e] = hi16(v1);
                bl[c][1][e] = hi16(lo_resid(v1));
            }
        }
        const float bv = isL1 ? (bih0[row] + bhh0[row]) : (bih1[row] + bhh1[row]);
        bsp[c] = (f32x4){bv, bv, bv, bv};
    }

    float cst[2][2];                     // c-state for this wave's row half [rl][p]
    cst[0][0] = cst[0][1] = cst[1][0] = cst[1][1] = 0.f;

    const float4* xg = (const float4*)x + (size_t)blockIdx.x * 16 * (T_LEN * 4);

    #pragma unroll 1
    for (int i = 0; i <= T_LEN; ++i) {
        if (i < T_LEN && (i & (TC - 1)) == 0) {
            __syncthreads();             // prior chunk's reads are done
            // stage x[t = i..i+15]: row b, 16 threads/row, coalesced float4
            const int b = tid >> 4, w = tid & 15;
            const float4* src = xg + (size_t)b * (T_LEN * 4) + (size_t)i * 4;
            short* dx = &sx[b * XSTR];
            #pragma unroll
            for (int ii = 0; ii < 4; ++ii) {
                const int el = ii * 16 + w;          // float4 index in chunk row
                const int t4 = el >> 2, f4 = el & 3;
                const float4 v = src[el];
                uint2 hp, lp;
                hp.x = permhi(v.y, v.x);
                hp.y = permhi(v.w, v.z);
                lp.x = permhi(lo_resid(v.y), lo_resid(v.x));
                lp.y = permhi(lo_resid(v.w), lo_resid(v.z));
                *(uint2*)&dx[t4 * 32 + f4 * 4]      = hp;
                *(uint2*)&dx[t4 * 32 + 16 + f4 * 4] = lp;
            }
        }
        __syncthreads();

        f32x4 g[8];
        bool active = false;

        if (isL1) {
            if (i < T_LEN) {
                active = true;
                const int t = i, tt = t & (TC - 1);
                const int ps = (t + 1) & 1;
                const short8 a0h = *(const short8*)&sh1hi[ps][n * HSTR + q * 8];
                const short8 a0l = *(const short8*)&sh1lo[ps][n * HSTR + q * 8];
                const short8 a1p = *(const short8*)&sx[n * XSTR + tt * 32 + q * 8];
                #pragma unroll
                for (int c = 0; c < 8; ++c) {
                    f32x4 acc = mfma16(a0h, bh[c][0], bsp[c]);
                    acc = mfma16(a0l, bh[c][0], acc);
                    acc = mfma16(a0h, bl[c][0], acc);
                    acc = mfma16(a1p, bh[c][1], acc);
                    acc = mfma16(a1p, bl[c][1], acc);
                    g[c] = acc;
                }
            }
        } else {
            if (i >= 1) {
                active = true;
                const int t = i - 1;
                const int cs = t & 1;
                const short8 a0h = *(const short8*)&sh1hi[cs][n * HSTR + q * 8];
                const short8 a0l = *(const short8*)&sh1lo[cs][n * HSTR + q * 8];
                const short8 a1h = *(const short8*)&sh2hi[n * HSTR + q * 8];
                const short8 a1l = *(const short8*)&sh2lo[n * HSTR + q * 8];
                #pragma unroll
                for (int c = 0; c < 8; ++c) {
                    f32x4 acc = mfma16(a0h, bh[c][0], bsp[c]);
                    acc = mfma16(a1h, bh[c][1], acc);
                    acc = mfma16(a0l, bh[c][0], acc);
                    acc = mfma16(a1l, bh[c][1], acc);
                    acc = mfma16(a0h, bl[c][0], acc);
                    acc = mfma16(a1h, bl[c][1], acc);
                    g[c] = acc;
                }
            }
        }

        if (active) {
            // select this wave's two C-rows at compile-time indices (uniform branch)
            float ga[8][2];
            if (rbase == 0) {
                #pragma unroll
                for (int c = 0; c < 8; ++c) { ga[c][0] = g[c][0]; ga[c][1] = g[c][1]; }
            } else {
                #pragma unroll
                for (int c = 0; c < 8; ++c) { ga[c][0] = g[c][2]; ga[c][1] = g[c][3]; }
            }
            const int t  = isL1 ? i : (i - 1);
            const int cs = t & 1;
            short* dsthi = isL1 ? sh1hi[cs] : sh2hi;
            short* dstlo = isL1 ? sh1lo[cs] : sh2lo;
            #pragma unroll
            for (int rl = 0; rl < 2; ++rl) {
                float hv[2];
                #pragma unroll
                for (int p = 0; p < 2; ++p) {
                    const float ig = fsig(ga[0 + p][rl]);
                    const float fg = fsig(ga[2 + p][rl]);
                    const float gg = ftanh(ga[4 + p][rl]);
                    const float og = fsig(ga[6 + p][rl]);
                    const float cc = fg * cst[rl][p] + ig * gg;
                    cst[rl][p] = cc;
                    hv[p] = og * ftanh(cc);
                }
                const int ro = (q * 4 + rbase + rl) * HSTR + 2 * n;
                *(unsigned*)&dsthi[ro] = permhi(hv[1], hv[0]);
                *(unsigned*)&dstlo[ro] = permhi(lo_resid(hv[1]), lo_resid(hv[0]));
            }
        }
    }

    __syncthreads();

    // ---- MLP head on h2_{T-1} ----
    if (wid == 2 && lane < 16) {
        float h2v[32];
        #pragma unroll
        for (int kk = 0; kk < 32; ++kk) {
            h2v[kk] = __uint_as_float(((unsigned)(unsigned short)sh2hi[lane * HSTR + kk]) << 16)
                    + __uint_as_float(((unsigned)(unsigned short)sh2lo[lane * HSTR + kk]) << 16);
        }
        float pacc = b2[0];
        #pragma unroll 1
        for (int jj = 0; jj < 16; ++jj) {
            float acc = b1[jj];
            #pragma unroll
            for (int kk = 0; kk < 32; ++kk) acc += W1[jj * 32 + kk] * h2v[kk];
            pacc += W2[jj] * fmaxf(acc, 0.f);
        }
        out[blockIdx.x * 16 + lane] = pacc;
    }
}

} // namespace

extern "C" void kernel_launch(void* const* d_in, const int* in_sizes, int n_in,
                              void* d_out, int out_size, void* d_ws, size_t ws_size,
                              hipStream_t stream) {
    const float* x    = (const float*)d_in[0];
    const float* Wih0 = (const float*)d_in[1];
    const float* Whh0 = (const float*)d_in[2];
    const float* bih0 = (const float*)d_in[3];
    const float* bhh0 = (const float*)d_in[4];
    const float* Wih1 = (const float*)d_in[5];
    const float* Whh1 = (const float*)d_in[6];
    const float* bih1 = (const float*)d_in[7];
    const float* bhh1 = (const float*)d_in[8];
    const float* W1   = (const float*)d_in[9];
    const float* b1   = (const float*)d_in[10];
    const float* W2   = (const float*)d_in[11];
    const float* b2   = (const float*)d_in[12];

    const int batch  = out_size;            // 4096
    const int blocks = batch / 16;          // 256 blocks x 4 waves

    hipLaunchKernelGGL(lstm2_pipe4_kernel, dim3(blocks), dim3(256), 0, stream,
                       x, Wih0, Whh0, bih0, bhh0, Wih1, Whh1, bih1, bhh1,
                       W1, b1, W2, b2, (float*)d_out);
}